// Round 9
// baseline (90.800 us; speedup 1.0000x reference)
//
#include <hip/hip_runtime.h>
#include <hip/hip_bf16.h>

#define B_  4
#define T_  1024
#define H_  8
#define NTOK (B_*T_)

// workspace float offsets
#define CONST_OFF 512       // 48 (+pad)
#define UTH_OFF   576       // 48x512 bf16 = 12288 float slots
#define UTL_OFF   12864     // 12288
#define XHI_OFF   25152     // 4096x512 bf16 = 1048576 float slots   (aliased by AOh)
#define XLO_OFF   1073728   // 1048576
#define WVTH_OFF  2122304   // 512x512 bf16 = 131072 float slots
#define WVTL_OFF  2253376
#define WOTH_OFF  2384448
#define WOTL_OFF  2515520
#define S_OFF     2646592   // 48x4096 fp32 (EXP2 of plane values)
#define VT_OFF    2843200   // 32x64x1024 bf16
// end 3,891,776 floats ~= 15.6 MB

#define LOG2E 1.4426950408889634f
#define LN2SQ 0.4804530139182014f

typedef __attribute__((ext_vector_type(4))) float v4f;
typedef __attribute__((ext_vector_type(8))) short v8s;

__device__ inline short bf16r(float f) {
  union { float f; unsigned u; } v; v.f = f;
  return (short)((v.u + 0x7FFFu + ((v.u >> 16) & 1u)) >> 16);
}
__device__ inline float bf16f(short s) {
  union { unsigned u; float f; } v; v.u = ((unsigned)(unsigned short)s) << 16; return v.f;
}
__device__ inline unsigned cvt_pk_bf16(float lo, float hi) {
  unsigned r;
  asm("v_cvt_pk_bf16_f32 %0, %1, %2" : "=v"(r) : "v"(lo), "v"(hi));
  return r;
}

// ---------------------------------------------------------------------------
// Fused prep: [0,96) fold Wq/Wk against MLP-stack folds -> Ut hi/lo + consts;
// [96,1120) x fp32 -> bf16 hi/lo; [1120,1248) transpose+split Wv/Wo.
__global__ __launch_bounds__(256) void k_prep(
    const float* __restrict__ Wphi_in, const float* __restrict__ Wphi_out,
    const float* __restrict__ bphi_in, const float* __restrict__ bphi_out,
    const float* __restrict__ Wta, const float* __restrict__ bta,
    const float* __restrict__ Wtb, const float* __restrict__ btb,
    const float* __restrict__ Wtau_in, const float* __restrict__ Wtau_out,
    const float* __restrict__ btau_in, const float* __restrict__ btau_out,
    const float* __restrict__ Wq, const float* __restrict__ bq,
    const float* __restrict__ Wk, const float* __restrict__ bk,
    const float* __restrict__ x, const float* __restrict__ Wv, const float* __restrict__ Wo,
    short* __restrict__ Uth, short* __restrict__ Utl, float* __restrict__ consts,
    short* __restrict__ xh, short* __restrict__ xl,
    short* __restrict__ Wvh, short* __restrict__ Wvl,
    short* __restrict__ Woh, short* __restrict__ Wol) {
  __shared__ float wv[390];
  __shared__ float tile[64][65];
  int bx = blockIdx.x, t = threadIdx.x;
  if (bx < 96) {
    if (t < 128) {
      float wp = 0.f;
      for (int j = 0; j < 64; ++j) wp += Wphi_in[t*64+j] * Wphi_out[j];
      float wt = 0.f;
      for (int j = 0; j < 32; ++j) wt += Wtau_in[t*32+j] * Wtau_out[j];
      wv[t]       = wp;
      wv[128 + t] = Wta[t] + Wtb[t];     // T_SCALAR == 1
      wv[256 + t] = wt;
    } else if (t == 128) {
      float bp = bphi_out[0];
      for (int j = 0; j < 64; ++j) bp += bphi_in[j]*Wphi_out[j];
      float bt = btau_out[0];
      for (int j = 0; j < 32; ++j) bt += btau_in[j]*Wtau_out[j];
      wv[384] = bp;
      wv[385] = bta[0] + btb[0];
      wv[386] = bt;
    }
    __syncthreads();
    int idx = bx*256 + t;              // 0..24575
    int c = idx & 511;
    int s = idx >> 9;
    int h = s / 6, tt = s % 6;
    int qk = tt / 3;
    int which = tt % 3;
    float scale = (which == 2) ? LOG2E : -LOG2E;
    const float* W = qk ? Wk : Wq;
    const float* wvec = wv + which*128 + qk*64;
    const float* row = W + c*512 + h*64;
    float acc = 0.f;
    #pragma unroll 8
    for (int d = 0; d < 64; ++d) acc += row[d] * wvec[d];
    float v = acc * scale;
    short hi = bf16r(v);
    Uth[s*512 + c] = hi;
    Utl[s*512 + c] = bf16r(v - bf16f(hi));
    if (c == 0) {
      const float* bb = qk ? bk : bq;
      float cs = 0.f;
      for (int d = 0; d < 64; ++d) cs += bb[h*64+d] * wvec[d];
      if (qk == 0) cs += wv[384 + which];
      consts[s] = cs * scale;
    }
    return;
  }
  if (bx < 1120) {
    size_t i = (size_t)((bx-96)*256 + t) * 8;
    float4 a = *(const float4*)(x + i);
    float4 b = *(const float4*)(x + i + 4);
    float vals[8] = {a.x,a.y,a.z,a.w,b.x,b.y,b.z,b.w};
    v8s hi, lo;
    #pragma unroll
    for (int j = 0; j < 8; ++j) {
      short h = bf16r(vals[j]);
      hi[j] = h;
      lo[j] = bf16r(vals[j] - bf16f(h));
    }
    *(v8s*)(xh + i) = hi;
    *(v8s*)(xl + i) = lo;
    return;
  }
  int idx = bx - 1120;              // 0..127
  int z = idx >> 6, rem = idx & 63;
  int k0 = (rem >> 3)*64, n0 = (rem & 7)*64;
  const float* src = z ? Wo : Wv;
  short* dh = z ? Woh : Wvh;
  short* dl = z ? Wol : Wvl;
  int kr = t >> 2, cq = t & 3;
  #pragma unroll
  for (int i = 0; i < 4; ++i) {
    float4 v = *(const float4*)(src + (size_t)(k0+kr)*512 + n0 + cq*16 + i*4);
    tile[kr][cq*16+i*4+0] = v.x; tile[kr][cq*16+i*4+1] = v.y;
    tile[kr][cq*16+i*4+2] = v.z; tile[kr][cq*16+i*4+3] = v.w;
  }
  __syncthreads();
  int nr = t >> 2, ko = t & 3;
  v8s h0,h1,l0,l1;
  #pragma unroll
  for (int i = 0; i < 8; ++i) {
    float a = tile[ko*16+i][nr];
    float b = tile[ko*16+8+i][nr];
    short ha = bf16r(a), hb = bf16r(b);
    h0[i] = ha; l0[i] = bf16r(a - bf16f(ha));
    h1[i] = hb; l1[i] = bf16r(b - bf16f(hb));
  }
  size_t base = (size_t)(n0+nr)*512 + k0 + ko*16;
  *(v8s*)(dh + base) = h0; *(v8s*)(dh + base + 8) = h1;
  *(v8s*)(dl + base) = l0; *(v8s*)(dl + base + 8) = l1;
}

// ---------------------------------------------------------------------------
// No-LDS 2-product MFMA GEMM: C = Ah*(Bh+Bl) + bias. All fragments read
// directly from global (L2-resident panels) — zero barriers in the K-loop.
// MODE 0: fp32 C + bias.  MODE 1: bf16 VT[b*8+h][d][t] (BN=64 = one head).
template<int MODE>
__device__ __forceinline__ void gemm_body(char* smem, int mb, int nb,
    const short* __restrict__ Ah,
    const short* __restrict__ Bh, const short* __restrict__ Bl,
    const float* __restrict__ bias, float* __restrict__ C, short* __restrict__ VT) {
  int tid = threadIdx.x, l = tid & 63, ra = l & 15, kg = l >> 4;
  int w = tid >> 6, wr = w >> 1, wc = w & 1;
  v4f acc[2][2] = {};
  const short* gA  = Ah + (size_t)(mb*64 + wr*32 + ra)*512 + kg*8;
  const short* gBh = Bh + (size_t)(nb*64 + wc*32 + ra)*512 + kg*8;
  const short* gBl = Bl + (size_t)(nb*64 + wc*32 + ra)*512 + kg*8;
  #pragma unroll 4
  for (int k0 = 0; k0 < 512; k0 += 32) {
    v8s a0  = *(const v8s*)(gA + k0);
    v8s a1  = *(const v8s*)(gA + 16*512 + k0);
    v8s b0h = *(const v8s*)(gBh + k0);
    v8s b1h = *(const v8s*)(gBh + 16*512 + k0);
    v8s b0l = *(const v8s*)(gBl + k0);
    v8s b1l = *(const v8s*)(gBl + 16*512 + k0);
    acc[0][0] = __builtin_amdgcn_mfma_f32_16x16x32_bf16(a0, b0h, acc[0][0], 0, 0, 0);
    acc[0][0] = __builtin_amdgcn_mfma_f32_16x16x32_bf16(a0, b0l, acc[0][0], 0, 0, 0);
    acc[0][1] = __builtin_amdgcn_mfma_f32_16x16x32_bf16(a0, b1h, acc[0][1], 0, 0, 0);
    acc[0][1] = __builtin_amdgcn_mfma_f32_16x16x32_bf16(a0, b1l, acc[0][1], 0, 0, 0);
    acc[1][0] = __builtin_amdgcn_mfma_f32_16x16x32_bf16(a1, b0h, acc[1][0], 0, 0, 0);
    acc[1][0] = __builtin_amdgcn_mfma_f32_16x16x32_bf16(a1, b0l, acc[1][0], 0, 0, 0);
    acc[1][1] = __builtin_amdgcn_mfma_f32_16x16x32_bf16(a1, b1h, acc[1][1], 0, 0, 0);
    acc[1][1] = __builtin_amdgcn_mfma_f32_16x16x32_bf16(a1, b1l, acc[1][1], 0, 0, 0);
  }
  if constexpr (MODE == 0) {
    #pragma unroll
    for (int ni = 0; ni < 2; ++ni) {
      int n = nb*64 + wc*32 + ni*16 + ra;
      float bv_ = bias[n];
      #pragma unroll
      for (int mi = 0; mi < 2; ++mi) {
        int row = mb*64 + wr*32 + mi*16 + kg*4;
        #pragma unroll
        for (int r = 0; r < 4; ++r)
          C[(size_t)(row+r)*512 + n] = acc[mi][ni][r] + bv_;
      }
    }
  } else {
    float (*ldsT)[65] = (float(*)[65])(smem);
    #pragma unroll
    for (int ni = 0; ni < 2; ++ni) {
      int lc = wc*32 + ni*16 + ra;
      float bv_ = bias[nb*64 + lc];
      #pragma unroll
      for (int mi = 0; mi < 2; ++mi) {
        int lr = wr*32 + mi*16 + kg*4;
        #pragma unroll
        for (int r = 0; r < 4; ++r)
          ldsT[lc][lr+r] = acc[mi][ni][r] + bv_;
      }
    }
    __syncthreads();
    int d = tid >> 2, tq = tid & 3;
    v8s h0, h1;
    #pragma unroll
    for (int i = 0; i < 8; ++i) {
      h0[i] = bf16r(ldsT[d][tq*16+i]);
      h1[i] = bf16r(ldsT[d][tq*16+8+i]);
    }
    size_t base = ((size_t)(((mb>>4)*8 + nb)*64 + d))*1024 + (mb&15)*64 + tq*16;
    *(v8s*)(VT + base)     = h0;
    *(v8s*)(VT + base + 8) = h1;
  }
}

// ---------------------------------------------------------------------------
// E[s][tok] = exp2(x . Ut[s] + consts[s]) via split-bf16 MFMA; 16 rows/block.
// (kept 3-product: S errors amplify through exp2 -> logits)
__device__ __forceinline__ void S_body(char* smem, int mb,
    const short* __restrict__ xh, const short* __restrict__ xl,
    const short* __restrict__ Uth, const short* __restrict__ Utl,
    const float* __restrict__ consts, float* __restrict__ E) {
  float* red = (float*)smem;            // [3][64][12]
  int tid = threadIdx.x, w = tid >> 6, l = tid & 63, ra = l & 15, kg = l >> 4;
  v4f acc[3] = {{0,0,0,0},{0,0,0,0},{0,0,0,0}};
  const short* xa = xh + (size_t)(mb*16+ra)*512;
  const short* xb = xl + (size_t)(mb*16+ra)*512;
  #pragma unroll
  for (int ks = 0; ks < 4; ++ks) {
    int kk = w*128 + ks*32 + kg*8;
    v8s ah = *(const v8s*)(xa + kk);
    v8s al = *(const v8s*)(xb + kk);
    #pragma unroll
    for (int nf = 0; nf < 3; ++nf) {
      v8s bh = *(const v8s*)(Uth + (size_t)(nf*16+ra)*512 + kk);
      v8s bl = *(const v8s*)(Utl + (size_t)(nf*16+ra)*512 + kk);
      acc[nf] = __builtin_amdgcn_mfma_f32_16x16x32_bf16(ah, bh, acc[nf], 0, 0, 0);
      acc[nf] = __builtin_amdgcn_mfma_f32_16x16x32_bf16(ah, bl, acc[nf], 0, 0, 0);
      acc[nf] = __builtin_amdgcn_mfma_f32_16x16x32_bf16(al, bh, acc[nf], 0, 0, 0);
    }
  }
  if (w > 0) {
    #pragma unroll
    for (int nf = 0; nf < 3; ++nf) *(v4f*)(red + ((w-1)*64 + l)*12 + nf*4) = acc[nf];
  }
  __syncthreads();
  if (w == 0) {
    #pragma unroll
    for (int p = 0; p < 3; ++p)
      #pragma unroll
      for (int nf = 0; nf < 3; ++nf) acc[nf] += *(const v4f*)(red + (p*64 + l)*12 + nf*4);
    int t0 = mb*16 + kg*4;
    #pragma unroll
    for (int nf = 0; nf < 3; ++nf) {
      int s = nf*16 + ra;
      float cns = consts[s];
      v4f o;
      #pragma unroll
      for (int c = 0; c < 4; ++c) o[c] = __builtin_amdgcn_exp2f(acc[nf][c] + cns);
      *(v4f*)(E + (size_t)s*NTOK + t0) = o;
    }
  }
}

// Fused mid stage: [0,256) = S/E planes; [256,768) = V-GEMM (MODE 1).
__global__ __launch_bounds__(256) void k_mid(
    const short* __restrict__ xh, const short* __restrict__ xl,
    const short* __restrict__ Uth, const short* __restrict__ Utl,
    const float* __restrict__ consts, float* __restrict__ E,
    const short* __restrict__ Wvh, const short* __restrict__ Wvl,
    const float* __restrict__ bv, short* __restrict__ VT) {
  __shared__ __align__(16) char smem[16640];
  int bx = blockIdx.x;
  if (bx < 256) {
    S_body(smem, bx, xh, xl, Uth, Utl, consts, E);
  } else {
    int i = bx - 256;
    gemm_body<1>(smem, i >> 3, i & 7, xh, Wvh, Wvl, bv, nullptr, VT);
  }
}

// ---------------------------------------------------------------------------
__global__ __launch_bounds__(256) void k_out(
    const short* __restrict__ Ah,
    const short* __restrict__ Bh, const short* __restrict__ Bl,
    const float* __restrict__ bias, float* __restrict__ C) {
  gemm_body<0>(nullptr, blockIdx.x, blockIdx.y, Ah, Bh, Bl, bias, C, nullptr);
}

// ---------------------------------------------------------------------------
// MFMA flash attention (R5-exact inner loop, best measured): 32 q-rows/block,
// 4 B-frags shared across 2 A-frags, split-K x4, LDS combine. Emits AOh only
// (bf16) — the AO_lo term is below the out-GEMM's noise floor.
__global__ __launch_bounds__(256) void k_attn(const float* __restrict__ E,
                                              const short* __restrict__ VT,
                                              short* __restrict__ AOh) {
  __shared__ float red[3][64][40];
  int tid = threadIdx.x, w = tid >> 6, l = tid & 63, ra = l & 15, kg = l >> 4;
  int bh = blockIdx.y, b = bh >> 3, h = bh & 7;
  int q0 = blockIdx.x * 32;
  const float* Eb = E + (size_t)h*6*NTOK + b*T_;
  float eqp[2], eqc[2], eqt[2];
  #pragma unroll
  for (int ai = 0; ai < 2; ++ai) {
    eqp[ai] = Eb[q0 + ai*16 + ra];
    eqc[ai] = Eb[NTOK + q0 + ai*16 + ra];
    eqt[ai] = Eb[2*NTOK + q0 + ai*16 + ra];
  }
  const float* Ekp = Eb + 3*NTOK;
  const float* Ekc = Eb + 4*NTOK;
  const float* Ekt = Eb + 5*NTOK;
  const short* Vb = VT + (size_t)bh*64*1024 + (size_t)ra*1024;

  v4f acc[2][4] = {};
  v4f dacc[2] = {};
  v8s ones;
  #pragma unroll
  for (int j = 0; j < 8; ++j) ones[j] = (short)0x3F80;

  #pragma unroll 2
  for (int ks = 0; ks < 8; ++ks) {
    int kk = w*256 + ks*32 + kg*8;
    v4f p0 = *(const v4f*)&Ekp[kk], p1 = *(const v4f*)&Ekp[kk+4];
    v4f c0 = *(const v4f*)&Ekc[kk], c1 = *(const v4f*)&Ekc[kk+4];
    v4f t0 = *(const v4f*)&Ekt[kk], t1 = *(const v4f*)&Ekt[kk+4];
    v8s bfr[4];
    #pragma unroll
    for (int ni = 0; ni < 4; ++ni) bfr[ni] = *(const v8s*)(Vb + (size_t)ni*16*1024 + kk);
    #pragma unroll
    for (int ai = 0; ai < 2; ++ai) {
      float p8[8];
      #pragma unroll
      for (int j = 0; j < 8; ++j) {
        float Ep = (j < 4) ? p0[j] : p1[j-4];
        float Ec = (j < 4) ? c0[j] : c1[j-4];
        float Et = (j < 4) ? t0[j] : t1[j-4];
        float ephi = eqp[ai] * Ep;                               // e^{-a_phi}
        float ec   = eqc[ai] * Ec;                               // e^{-a_c}
        float g    = eqt[ai] * Et;                               // e^{a_tau}
        float ti   = __builtin_amdgcn_rcpf(1.f + ec);            // sigmoid(a_c)
        float t2   = __builtin_amdgcn_logf(1.f + g);             // softplus/ln2
        float z    = 1.f - __builtin_amdgcn_exp2f(-t2 * ti);
        float den  = (1.f + ephi) * fmaf(t2, LN2SQ, 6.93e-7f);
        p8[j] = __builtin_amdgcn_exp2f(z * __builtin_amdgcn_rcpf(den));
      }
      union { unsigned u[4]; v8s s; } af;
      af.u[0] = cvt_pk_bf16(p8[0], p8[1]);
      af.u[1] = cvt_pk_bf16(p8[2], p8[3]);
      af.u[2] = cvt_pk_bf16(p8[4], p8[5]);
      af.u[3] = cvt_pk_bf16(p8[6], p8[7]);
      v8s afrag = af.s;
      #pragma unroll
      for (int ni = 0; ni < 4; ++ni)
        acc[ai][ni] = __builtin_amdgcn_mfma_f32_16x16x32_bf16(afrag, bfr[ni], acc[ai][ni], 0, 0, 0);
      dacc[ai] = __builtin_amdgcn_mfma_f32_16x16x32_bf16(afrag, ones, dacc[ai], 0, 0, 0);
    }
  }

  if (w > 0) {
    float* rp = &red[w-1][l][0];
    #pragma unroll
    for (int ai = 0; ai < 2; ++ai) {
      #pragma unroll
      for (int ni = 0; ni < 4; ++ni) *(v4f*)(rp + ai*16 + ni*4) = acc[ai][ni];
      *(v4f*)(rp + 32 + ai*4) = dacc[ai];
    }
  }
  __syncthreads();
  if (w == 0) {
    #pragma unroll
    for (int p = 0; p < 3; ++p) {
      const float* rp = &red[p][l][0];
      #pragma unroll
      for (int ai = 0; ai < 2; ++ai) {
        #pragma unroll
        for (int ni = 0; ni < 4; ++ni) acc[ai][ni] += *(const v4f*)(rp + ai*16 + ni*4);
        dacc[ai] += *(const v4f*)(rp + 32 + ai*4);
      }
    }
    #pragma unroll
    for (int ai = 0; ai < 2; ++ai) {
      size_t qb = (size_t)(b*T_ + q0 + ai*16 + kg*4);
      #pragma unroll
      for (int r = 0; r < 4; ++r) {
        float inv = __builtin_amdgcn_rcpf(dacc[ai][r]);
        size_t o = (qb + r)*512 + h*64 + ra;
        #pragma unroll
        for (int ni = 0; ni < 4; ++ni)
          AOh[o + ni*16] = bf16r(acc[ai][ni][r] * inv);
      }
    }
  }
}

// ---------------------------------------------------------------------------
extern "C" void kernel_launch(void* const* d_in, const int* in_sizes, int n_in,
                              void* d_out, int out_size, void* d_ws, size_t ws_size,
                              hipStream_t stream) {
  (void)in_sizes; (void)n_in; (void)out_size; (void)ws_size;
  const float* x        = (const float*)d_in[0];
  const float* Wq       = (const float*)d_in[1];
  const float* bq       = (const float*)d_in[2];
  const float* Wk       = (const float*)d_in[3];
  const float* bk       = (const float*)d_in[4];
  const float* Wv       = (const float*)d_in[5];
  const float* bv       = (const float*)d_in[6];
  const float* Wphi_in  = (const float*)d_in[7];
  const float* bphi_in  = (const float*)d_in[8];
  const float* Wphi_out = (const float*)d_in[9];
  const float* bphi_out = (const float*)d_in[10];
  const float* Wta      = (const float*)d_in[11];
  const float* bta      = (const float*)d_in[12];
  const float* Wtb      = (const float*)d_in[13];
  const float* btb      = (const float*)d_in[14];
  const float* Wtau_in  = (const float*)d_in[15];
  const float* btau_in  = (const float*)d_in[16];
  const float* Wtau_out = (const float*)d_in[17];
  const float* btau_out = (const float*)d_in[18];
  const float* Wo       = (const float*)d_in[19];
  const float* bo       = (const float*)d_in[20];
  float* out = (float*)d_out;
  float* ws  = (float*)d_ws;

  float* consts = ws + CONST_OFF;
  short* Uth    = (short*)(ws + UTH_OFF);
  short* Utl    = (short*)(ws + UTL_OFF);
  short* xhi    = (short*)(ws + XHI_OFF);
  short* xlo    = (short*)(ws + XLO_OFF);
  short* AOh    = (short*)(ws + XHI_OFF);   // alias: x-splits dead after V-GEMM/S
  short* Wvth   = (short*)(ws + WVTH_OFF);
  short* Wvtl   = (short*)(ws + WVTL_OFF);
  short* Woth   = (short*)(ws + WOTH_OFF);
  short* Wotl   = (short*)(ws + WOTL_OFF);
  float* E      = ws + S_OFF;
  short* VT     = (short*)(ws + VT_OFF);

  hipLaunchKernelGGL(k_prep, dim3(1248), dim3(256), 0, stream,
                     Wphi_in, Wphi_out, bphi_in, bphi_out, Wta, bta, Wtb, btb,
                     Wtau_in, Wtau_out, btau_in, btau_out,
                     Wq, bq, Wk, bk, x, Wv, Wo,
                     Uth, Utl, consts, xhi, xlo, Wvth, Wvtl, Woth, Wotl);
  hipLaunchKernelGGL(k_mid, dim3(768), dim3(256), 0, stream,
                     xhi, xlo, Uth, Utl, consts, E, Wvth, Wvtl, bv, VT);
  hipLaunchKernelGGL(k_attn, dim3(T_/32, B_*H_), dim3(256), 0, stream, E, VT, AOh);
  hipLaunchKernelGGL(k_out, dim3(NTOK/64, 8), dim3(256), 0, stream,
                     AOh, Woth, Wotl, bo, out);
}

// Round 10
// 62.839 us; speedup vs baseline: 1.4450x; 1.4450x over previous
//
#include <hip/hip_runtime.h>
#include <hip/hip_bf16.h>

#define B_  4
#define T_  1024
#define H_  8
#define NTOK (B_*T_)

// workspace float offsets
#define CONST_OFF 512       // 48 (+pad)
#define UTH_OFF   576       // 48x512 bf16 = 12288 float slots
#define UTL_OFF   12864     // 12288
#define XHI_OFF   25152     // 4096x512 bf16 = 1048576 float slots   (aliased by AOh)
#define XLO_OFF   1073728   // 1048576
#define WVTH_OFF  2122304   // 512x512 bf16 = 131072 float slots
#define WVTL_OFF  2253376
#define WOTH_OFF  2384448
#define WOTL_OFF  2515520
#define S_OFF     2646592   // 48x4096 fp32 (EXP2 of plane values)
#define VT_OFF    2843200   // 32x64x1024 bf16
// end 3,891,776 floats ~= 15.6 MB

#define LOG2E 1.4426950408889634f
#define LN2SQ 0.4804530139182014f

typedef __attribute__((ext_vector_type(4))) float v4f;
typedef __attribute__((ext_vector_type(8))) short v8s;

__device__ inline short bf16r(float f) {
  union { float f; unsigned u; } v; v.f = f;
  return (short)((v.u + 0x7FFFu + ((v.u >> 16) & 1u)) >> 16);
}
__device__ inline float bf16f(short s) {
  union { unsigned u; float f; } v; v.u = ((unsigned)(unsigned short)s) << 16; return v.f;
}
__device__ inline unsigned cvt_pk_bf16(float lo, float hi) {
  unsigned r;
  asm("v_cvt_pk_bf16_f32 %0, %1, %2" : "=v"(r) : "v"(lo), "v"(hi));
  return r;
}

// ---------------------------------------------------------------------------
// Fused prep: [0,96) fold Wq/Wk against MLP-stack folds -> Ut hi/lo + consts;
// [96,1120) x fp32 -> bf16 hi/lo; [1120,1248) transpose+split Wv/Wo.
__global__ __launch_bounds__(256) void k_prep(
    const float* __restrict__ Wphi_in, const float* __restrict__ Wphi_out,
    const float* __restrict__ bphi_in, const float* __restrict__ bphi_out,
    const float* __restrict__ Wta, const float* __restrict__ bta,
    const float* __restrict__ Wtb, const float* __restrict__ btb,
    const float* __restrict__ Wtau_in, const float* __restrict__ Wtau_out,
    const float* __restrict__ btau_in, const float* __restrict__ btau_out,
    const float* __restrict__ Wq, const float* __restrict__ bq,
    const float* __restrict__ Wk, const float* __restrict__ bk,
    const float* __restrict__ x, const float* __restrict__ Wv, const float* __restrict__ Wo,
    short* __restrict__ Uth, short* __restrict__ Utl, float* __restrict__ consts,
    short* __restrict__ xh, short* __restrict__ xl,
    short* __restrict__ Wvh, short* __restrict__ Wvl,
    short* __restrict__ Woh, short* __restrict__ Wol) {
  __shared__ float wv[390];
  __shared__ float tile[64][65];
  int bx = blockIdx.x, t = threadIdx.x;
  if (bx < 96) {
    if (t < 128) {
      float wp = 0.f;
      for (int j = 0; j < 64; ++j) wp += Wphi_in[t*64+j] * Wphi_out[j];
      float wt = 0.f;
      for (int j = 0; j < 32; ++j) wt += Wtau_in[t*32+j] * Wtau_out[j];
      wv[t]       = wp;
      wv[128 + t] = Wta[t] + Wtb[t];     // T_SCALAR == 1
      wv[256 + t] = wt;
    } else if (t == 128) {
      float bp = bphi_out[0];
      for (int j = 0; j < 64; ++j) bp += bphi_in[j]*Wphi_out[j];
      float bt = btau_out[0];
      for (int j = 0; j < 32; ++j) bt += btau_in[j]*Wtau_out[j];
      wv[384] = bp;
      wv[385] = bta[0] + btb[0];
      wv[386] = bt;
    }
    __syncthreads();
    int idx = bx*256 + t;              // 0..24575
    int c = idx & 511;
    int s = idx >> 9;
    int h = s / 6, tt = s % 6;
    int qk = tt / 3;
    int which = tt % 3;
    float scale = (which == 2) ? LOG2E : -LOG2E;
    const float* W = qk ? Wk : Wq;
    const float* wvec = wv + which*128 + qk*64;
    const float* row = W + c*512 + h*64;
    float acc = 0.f;
    #pragma unroll 8
    for (int d = 0; d < 64; ++d) acc += row[d] * wvec[d];
    float v = acc * scale;
    short hi = bf16r(v);
    Uth[s*512 + c] = hi;
    Utl[s*512 + c] = bf16r(v - bf16f(hi));
    if (c == 0) {
      const float* bb = qk ? bk : bq;
      float cs = 0.f;
      for (int d = 0; d < 64; ++d) cs += bb[h*64+d] * wvec[d];
      if (qk == 0) cs += wv[384 + which];
      consts[s] = cs * scale;
    }
    return;
  }
  if (bx < 1120) {
    size_t i = (size_t)((bx-96)*256 + t) * 8;
    float4 a = *(const float4*)(x + i);
    float4 b = *(const float4*)(x + i + 4);
    float vals[8] = {a.x,a.y,a.z,a.w,b.x,b.y,b.z,b.w};
    v8s hi, lo;
    #pragma unroll
    for (int j = 0; j < 8; ++j) {
      short h = bf16r(vals[j]);
      hi[j] = h;
      lo[j] = bf16r(vals[j] - bf16f(h));
    }
    *(v8s*)(xh + i) = hi;
    *(v8s*)(xl + i) = lo;
    return;
  }
  int idx = bx - 1120;              // 0..127
  int z = idx >> 6, rem = idx & 63;
  int k0 = (rem >> 3)*64, n0 = (rem & 7)*64;
  const float* src = z ? Wo : Wv;
  short* dh = z ? Woh : Wvh;
  short* dl = z ? Wol : Wvl;
  int kr = t >> 2, cq = t & 3;
  #pragma unroll
  for (int i = 0; i < 4; ++i) {
    float4 v = *(const float4*)(src + (size_t)(k0+kr)*512 + n0 + cq*16 + i*4);
    tile[kr][cq*16+i*4+0] = v.x; tile[kr][cq*16+i*4+1] = v.y;
    tile[kr][cq*16+i*4+2] = v.z; tile[kr][cq*16+i*4+3] = v.w;
  }
  __syncthreads();
  int nr = t >> 2, ko = t & 3;
  v8s h0,h1,l0,l1;
  #pragma unroll
  for (int i = 0; i < 8; ++i) {
    float a = tile[ko*16+i][nr];
    float b = tile[ko*16+8+i][nr];
    short ha = bf16r(a), hb = bf16r(b);
    h0[i] = ha; l0[i] = bf16r(a - bf16f(ha));
    h1[i] = hb; l1[i] = bf16r(b - bf16f(hb));
  }
  size_t base = (size_t)(n0+nr)*512 + k0 + ko*16;
  *(v8s*)(dh + base) = h0; *(v8s*)(dh + base + 8) = h1;
  *(v8s*)(dl + base) = l0; *(v8s*)(dl + base + 8) = l1;
}

// ---------------------------------------------------------------------------
// LDS-staged 2-product MFMA GEMM: C = A*(Bh+Bl) + bias (A single bf16 plane).
// Register-prefetch of next K-tile; 3 staged arrays; 8 MFMA / K-step.
// MODE 0: fp32 C + bias.  MODE 1: bf16 VT[b*8+h][d][t] (BN=64 = one head).
template<int MODE>
__device__ __forceinline__ void gemm_body(char* smem, int mb, int nb,
    const short* __restrict__ A,
    const short* __restrict__ Bh, const short* __restrict__ Bl,
    const float* __restrict__ bias, float* __restrict__ C, short* __restrict__ VT) {
  short (*As)[40]   = (short(*)[40])(smem);
  short (*Bs_h)[40] = (short(*)[40])(smem + 5120);
  short (*Bs_l)[40] = (short(*)[40])(smem + 10240);
  int tid = threadIdx.x, l = tid & 63, ra = l & 15, kg = l >> 4;
  int w = tid >> 6, wr = w >> 1, wc = w & 1;
  v4f acc[2][2] = {};
  int srow = tid >> 2, soct = tid & 3;
  const short* gA  = A  + (size_t)(mb*64+srow)*512 + soct*8;
  const short* gBh = Bh + (size_t)(nb*64+srow)*512 + soct*8;
  const short* gBl = Bl + (size_t)(nb*64+srow)*512 + soct*8;
  v8s sa = *(const v8s*)(gA);
  v8s sc = *(const v8s*)(gBh);
  v8s sd = *(const v8s*)(gBl);
  for (int k0 = 0; k0 < 512; k0 += 32) {
    __syncthreads();
    *(v8s*)&As[srow][soct*8]   = sa;
    *(v8s*)&Bs_h[srow][soct*8] = sc;
    *(v8s*)&Bs_l[srow][soct*8] = sd;
    if (k0 < 480) {                       // prefetch next K-tile into regs
      sa = *(const v8s*)(gA + k0 + 32);
      sc = *(const v8s*)(gBh + k0 + 32);
      sd = *(const v8s*)(gBl + k0 + 32);
    }
    __syncthreads();
    v8s a[2], bh[2], bl[2];
    #pragma unroll
    for (int mi = 0; mi < 2; ++mi)
      a[mi] = *(const v8s*)&As[wr*32 + mi*16 + ra][kg*8];
    #pragma unroll
    for (int ni = 0; ni < 2; ++ni) {
      int r = wc*32 + ni*16 + ra;
      bh[ni] = *(const v8s*)&Bs_h[r][kg*8];
      bl[ni] = *(const v8s*)&Bs_l[r][kg*8];
    }
    #pragma unroll
    for (int mi = 0; mi < 2; ++mi)
      #pragma unroll
      for (int ni = 0; ni < 2; ++ni) {
        acc[mi][ni] = __builtin_amdgcn_mfma_f32_16x16x32_bf16(a[mi], bh[ni], acc[mi][ni], 0, 0, 0);
        acc[mi][ni] = __builtin_amdgcn_mfma_f32_16x16x32_bf16(a[mi], bl[ni], acc[mi][ni], 0, 0, 0);
      }
  }
  if constexpr (MODE == 0) {
    #pragma unroll
    for (int ni = 0; ni < 2; ++ni) {
      int n = nb*64 + wc*32 + ni*16 + ra;
      float bv_ = bias[n];
      #pragma unroll
      for (int mi = 0; mi < 2; ++mi) {
        int row = mb*64 + wr*32 + mi*16 + kg*4;
        #pragma unroll
        for (int r = 0; r < 4; ++r)
          C[(size_t)(row+r)*512 + n] = acc[mi][ni][r] + bv_;
      }
    }
  } else {
    __syncthreads();                      // staging reads done; alias ldsT
    float (*ldsT)[65] = (float(*)[65])(smem);
    #pragma unroll
    for (int ni = 0; ni < 2; ++ni) {
      int lc = wc*32 + ni*16 + ra;
      float bv_ = bias[nb*64 + lc];
      #pragma unroll
      for (int mi = 0; mi < 2; ++mi) {
        int lr = wr*32 + mi*16 + kg*4;
        #pragma unroll
        for (int r = 0; r < 4; ++r)
          ldsT[lc][lr+r] = acc[mi][ni][r] + bv_;
      }
    }
    __syncthreads();
    int d = tid >> 2, tq = tid & 3;
    v8s h0, h1;
    #pragma unroll
    for (int i = 0; i < 8; ++i) {
      h0[i] = bf16r(ldsT[d][tq*16+i]);
      h1[i] = bf16r(ldsT[d][tq*16+8+i]);
    }
    size_t base = ((size_t)(((mb>>4)*8 + nb)*64 + d))*1024 + (mb&15)*64 + tq*16;
    *(v8s*)(VT + base)     = h0;
    *(v8s*)(VT + base + 8) = h1;
  }
}

// ---------------------------------------------------------------------------
// E[s][tok] = exp2(x . Ut[s] + consts[s]) via split-bf16 MFMA; 16 rows/block.
// (kept 3-product: S errors amplify through exp2 -> logits)
__device__ __forceinline__ void S_body(char* smem, int mb,
    const short* __restrict__ xh, const short* __restrict__ xl,
    const short* __restrict__ Uth, const short* __restrict__ Utl,
    const float* __restrict__ consts, float* __restrict__ E) {
  float* red = (float*)smem;            // [3][64][12]
  int tid = threadIdx.x, w = tid >> 6, l = tid & 63, ra = l & 15, kg = l >> 4;
  v4f acc[3] = {{0,0,0,0},{0,0,0,0},{0,0,0,0}};
  const short* xa = xh + (size_t)(mb*16+ra)*512;
  const short* xb = xl + (size_t)(mb*16+ra)*512;
  #pragma unroll
  for (int ks = 0; ks < 4; ++ks) {
    int kk = w*128 + ks*32 + kg*8;
    v8s ah = *(const v8s*)(xa + kk);
    v8s al = *(const v8s*)(xb + kk);
    #pragma unroll
    for (int nf = 0; nf < 3; ++nf) {
      v8s bh = *(const v8s*)(Uth + (size_t)(nf*16+ra)*512 + kk);
      v8s bl = *(const v8s*)(Utl + (size_t)(nf*16+ra)*512 + kk);
      acc[nf] = __builtin_amdgcn_mfma_f32_16x16x32_bf16(ah, bh, acc[nf], 0, 0, 0);
      acc[nf] = __builtin_amdgcn_mfma_f32_16x16x32_bf16(ah, bl, acc[nf], 0, 0, 0);
      acc[nf] = __builtin_amdgcn_mfma_f32_16x16x32_bf16(al, bh, acc[nf], 0, 0, 0);
    }
  }
  if (w > 0) {
    #pragma unroll
    for (int nf = 0; nf < 3; ++nf) *(v4f*)(red + ((w-1)*64 + l)*12 + nf*4) = acc[nf];
  }
  __syncthreads();
  if (w == 0) {
    #pragma unroll
    for (int p = 0; p < 3; ++p)
      #pragma unroll
      for (int nf = 0; nf < 3; ++nf) acc[nf] += *(const v4f*)(red + (p*64 + l)*12 + nf*4);
    int t0 = mb*16 + kg*4;
    #pragma unroll
    for (int nf = 0; nf < 3; ++nf) {
      int s = nf*16 + ra;
      float cns = consts[s];
      v4f o;
      #pragma unroll
      for (int c = 0; c < 4; ++c) o[c] = __builtin_amdgcn_exp2f(acc[nf][c] + cns);
      *(v4f*)(E + (size_t)s*NTOK + t0) = o;
    }
  }
}

// Fused mid stage: [0,256) = S/E planes; [256,768) = V-GEMM (MODE 1).
__global__ __launch_bounds__(256) void k_mid(
    const short* __restrict__ xh, const short* __restrict__ xl,
    const short* __restrict__ Uth, const short* __restrict__ Utl,
    const float* __restrict__ consts, float* __restrict__ E,
    const short* __restrict__ Wvh, const short* __restrict__ Wvl,
    const float* __restrict__ bv, short* __restrict__ VT) {
  __shared__ __align__(16) char smem[16640];
  int bx = blockIdx.x;
  if (bx < 256) {
    S_body(smem, bx, xh, xl, Uth, Utl, consts, E);
  } else {
    int i = bx - 256;
    gemm_body<1>(smem, i >> 3, i & 7, xh, Wvh, Wvl, bv, nullptr, VT);
  }
}

// ---------------------------------------------------------------------------
__global__ __launch_bounds__(256) void k_out(
    const short* __restrict__ A,
    const short* __restrict__ Bh, const short* __restrict__ Bl,
    const float* __restrict__ bias, float* __restrict__ C) {
  __shared__ __align__(16) char smem[16640];
  gemm_body<0>(smem, blockIdx.x, blockIdx.y, A, Bh, Bl, bias, C, nullptr);
}

// ---------------------------------------------------------------------------
// MFMA flash attention (R5-exact inner loop, best measured): 32 q-rows/block,
// 4 B-frags shared across 2 A-frags, split-K x4, LDS combine. Emits AOh only.
__global__ __launch_bounds__(256) void k_attn(const float* __restrict__ E,
                                              const short* __restrict__ VT,
                                              short* __restrict__ AOh) {
  __shared__ float red[3][64][40];
  int tid = threadIdx.x, w = tid >> 6, l = tid & 63, ra = l & 15, kg = l >> 4;
  int bh = blockIdx.y, b = bh >> 3, h = bh & 7;
  int q0 = blockIdx.x * 32;
  const float* Eb = E + (size_t)h*6*NTOK + b*T_;
  float eqp[2], eqc[2], eqt[2];
  #pragma unroll
  for (int ai = 0; ai < 2; ++ai) {
    eqp[ai] = Eb[q0 + ai*16 + ra];
    eqc[ai] = Eb[NTOK + q0 + ai*16 + ra];
    eqt[ai] = Eb[2*NTOK + q0 + ai*16 + ra];
  }
  const float* Ekp = Eb + 3*NTOK;
  const float* Ekc = Eb + 4*NTOK;
  const float* Ekt = Eb + 5*NTOK;
  const short* Vb = VT + (size_t)bh*64*1024 + (size_t)ra*1024;

  v4f acc[2][4] = {};
  v4f dacc[2] = {};
  v8s ones;
  #pragma unroll
  for (int j = 0; j < 8; ++j) ones[j] = (short)0x3F80;

  #pragma unroll 2
  for (int ks = 0; ks < 8; ++ks) {
    int kk = w*256 + ks*32 + kg*8;
    v4f p0 = *(const v4f*)&Ekp[kk], p1 = *(const v4f*)&Ekp[kk+4];
    v4f c0 = *(const v4f*)&Ekc[kk], c1 = *(const v4f*)&Ekc[kk+4];
    v4f t0 = *(const v4f*)&Ekt[kk], t1 = *(const v4f*)&Ekt[kk+4];
    v8s bfr[4];
    #pragma unroll
    for (int ni = 0; ni < 4; ++ni) bfr[ni] = *(const v8s*)(Vb + (size_t)ni*16*1024 + kk);
    #pragma unroll
    for (int ai = 0; ai < 2; ++ai) {
      float p8[8];
      #pragma unroll
      for (int j = 0; j < 8; ++j) {
        float Ep = (j < 4) ? p0[j] : p1[j-4];
        float Ec = (j < 4) ? c0[j] : c1[j-4];
        float Et = (j < 4) ? t0[j] : t1[j-4];
        float ephi = eqp[ai] * Ep;                               // e^{-a_phi}
        float ec   = eqc[ai] * Ec;                               // e^{-a_c}
        float g    = eqt[ai] * Et;                               // e^{a_tau}
        float ti   = __builtin_amdgcn_rcpf(1.f + ec);            // sigmoid(a_c)
        float t2   = __builtin_amdgcn_logf(1.f + g);             // softplus/ln2
        float z    = 1.f - __builtin_amdgcn_exp2f(-t2 * ti);
        float den  = (1.f + ephi) * fmaf(t2, LN2SQ, 6.93e-7f);
        p8[j] = __builtin_amdgcn_exp2f(z * __builtin_amdgcn_rcpf(den));
      }
      union { unsigned u[4]; v8s s; } af;
      af.u[0] = cvt_pk_bf16(p8[0], p8[1]);
      af.u[1] = cvt_pk_bf16(p8[2], p8[3]);
      af.u[2] = cvt_pk_bf16(p8[4], p8[5]);
      af.u[3] = cvt_pk_bf16(p8[6], p8[7]);
      v8s afrag = af.s;
      #pragma unroll
      for (int ni = 0; ni < 4; ++ni)
        acc[ai][ni] = __builtin_amdgcn_mfma_f32_16x16x32_bf16(afrag, bfr[ni], acc[ai][ni], 0, 0, 0);
      dacc[ai] = __builtin_amdgcn_mfma_f32_16x16x32_bf16(afrag, ones, dacc[ai], 0, 0, 0);
    }
  }

  if (w > 0) {
    float* rp = &red[w-1][l][0];
    #pragma unroll
    for (int ai = 0; ai < 2; ++ai) {
      #pragma unroll
      for (int ni = 0; ni < 4; ++ni) *(v4f*)(rp + ai*16 + ni*4) = acc[ai][ni];
      *(v4f*)(rp + 32 + ai*4) = dacc[ai];
    }
  }
  __syncthreads();
  if (w == 0) {
    #pragma unroll
    for (int p = 0; p < 3; ++p) {
      const float* rp = &red[p][l][0];
      #pragma unroll
      for (int ai = 0; ai < 2; ++ai) {
        #pragma unroll
        for (int ni = 0; ni < 4; ++ni) acc[ai][ni] += *(const v4f*)(rp + ai*16 + ni*4);
        dacc[ai] += *(const v4f*)(rp + 32 + ai*4);
      }
    }
    #pragma unroll
    for (int ai = 0; ai < 2; ++ai) {
      size_t qb = (size_t)(b*T_ + q0 + ai*16 + kg*4);
      #pragma unroll
      for (int r = 0; r < 4; ++r) {
        float inv = __builtin_amdgcn_rcpf(dacc[ai][r]);
        size_t o = (qb + r)*512 + h*64 + ra;
        #pragma unroll
        for (int ni = 0; ni < 4; ++ni)
          AOh[o + ni*16] = bf16r(acc[ai][ni][r] * inv);
      }
    }
  }
}

// ---------------------------------------------------------------------------
extern "C" void kernel_launch(void* const* d_in, const int* in_sizes, int n_in,
                              void* d_out, int out_size, void* d_ws, size_t ws_size,
                              hipStream_t stream) {
  (void)in_sizes; (void)n_in; (void)out_size; (void)ws_size;
  const float* x        = (const float*)d_in[0];
  const float* Wq       = (const float*)d_in[1];
  const float* bq       = (const float*)d_in[2];
  const float* Wk       = (const float*)d_in[3];
  const float* bk       = (const float*)d_in[4];
  const float* Wv       = (const float*)d_in[5];
  const float* bv       = (const float*)d_in[6];
  const float* Wphi_in  = (const float*)d_in[7];
  const float* bphi_in  = (const float*)d_in[8];
  const float* Wphi_out = (const float*)d_in[9];
  const float* bphi_out = (const float*)d_in[10];
  const float* Wta      = (const float*)d_in[11];
  const float* bta      = (const float*)d_in[12];
  const float* Wtb      = (const float*)d_in[13];
  const float* btb      = (const float*)d_in[14];
  const float* Wtau_in  = (const float*)d_in[15];
  const float* btau_in  = (const float*)d_in[16];
  const float* Wtau_out = (const float*)d_in[17];
  const float* btau_out = (const float*)d_in[18];
  const float* Wo       = (const float*)d_in[19];
  const float* bo       = (const float*)d_in[20];
  float* out = (float*)d_out;
  float* ws  = (float*)d_ws;

  float* consts = ws + CONST_OFF;
  short* Uth    = (short*)(ws + UTH_OFF);
  short* Utl    = (short*)(ws + UTL_OFF);
  short* xhi    = (short*)(ws + XHI_OFF);
  short* xlo    = (short*)(ws + XLO_OFF);
  short* AOh    = (short*)(ws + XHI_OFF);   // alias: x-splits dead after V-GEMM/S
  short* Wvth   = (short*)(ws + WVTH_OFF);
  short* Wvtl   = (short*)(ws + WVTL_OFF);
  short* Woth   = (short*)(ws + WOTH_OFF);
  short* Wotl   = (short*)(ws + WOTL_OFF);
  float* E      = ws + S_OFF;
  short* VT     = (short*)(ws + VT_OFF);

  hipLaunchKernelGGL(k_prep, dim3(1248), dim3(256), 0, stream,
                     Wphi_in, Wphi_out, bphi_in, bphi_out, Wta, bta, Wtb, btb,
                     Wtau_in, Wtau_out, btau_in, btau_out,
                     Wq, bq, Wk, bk, x, Wv, Wo,
                     Uth, Utl, consts, xhi, xlo, Wvth, Wvtl, Woth, Wotl);
  hipLaunchKernelGGL(k_mid, dim3(768), dim3(256), 0, stream,
                     xhi, xlo, Uth, Utl, consts, E, Wvth, Wvtl, bv, VT);
  hipLaunchKernelGGL(k_attn, dim3(T_/32, B_*H_), dim3(256), 0, stream, E, VT, AOh);
  hipLaunchKernelGGL(k_out, dim3(NTOK/64, 8), dim3(256), 0, stream,
                     AOh, Woth, Wotl, bo, out);
}

// Round 11
// 57.230 us; speedup vs baseline: 1.5866x; 1.0980x over previous
//
#include <hip/hip_runtime.h>
#include <hip/hip_bf16.h>

#define B_  4
#define T_  1024
#define H_  8
#define NTOK (B_*T_)

// workspace float offsets
#define CONST_OFF 512       // 48 (+pad)
#define UTH_OFF   576       // 48x512 bf16 = 12288 float slots
#define UTL_OFF   12864     // 12288
#define XHI_OFF   25152     // 4096x512 bf16 = 1048576 float slots   (aliased by AOh)
#define WVTH_OFF  2122304   // 512x512 bf16 = 131072 float slots
#define WOTH_OFF  2384448
#define S_OFF     2646592   // 48x4096 fp32 (EXP2 of plane values)
#define VT_OFF    2843200   // 32x64x1024 bf16
// end 3,891,776 floats ~= 15.6 MB

#define LOG2E 1.4426950408889634f
#define LN2SQ 0.4804530139182014f

typedef __attribute__((ext_vector_type(4))) float v4f;
typedef __attribute__((ext_vector_type(8))) short v8s;

__device__ inline short bf16r(float f) {
  union { float f; unsigned u; } v; v.f = f;
  return (short)((v.u + 0x7FFFu + ((v.u >> 16) & 1u)) >> 16);
}
__device__ inline float bf16f(short s) {
  union { unsigned u; float f; } v; v.u = ((unsigned)(unsigned short)s) << 16; return v.f;
}
__device__ inline unsigned cvt_pk_bf16(float lo, float hi) {
  unsigned r;
  asm("v_cvt_pk_bf16_f32 %0, %1, %2" : "=v"(r) : "v"(lo), "v"(hi));
  return r;
}

// ---------------------------------------------------------------------------
// Fused prep: [0,96) fold Wq/Wk against MLP-stack folds -> Ut hi/lo + consts;
// [96,1120) x fp32 -> bf16 hi; [1120,1248) transpose Wv/Wo -> bf16 hi [n][k].
__global__ __launch_bounds__(256) void k_prep(
    const float* __restrict__ Wphi_in, const float* __restrict__ Wphi_out,
    const float* __restrict__ bphi_in, const float* __restrict__ bphi_out,
    const float* __restrict__ Wta, const float* __restrict__ bta,
    const float* __restrict__ Wtb, const float* __restrict__ btb,
    const float* __restrict__ Wtau_in, const float* __restrict__ Wtau_out,
    const float* __restrict__ btau_in, const float* __restrict__ btau_out,
    const float* __restrict__ Wq, const float* __restrict__ bq,
    const float* __restrict__ Wk, const float* __restrict__ bk,
    const float* __restrict__ x, const float* __restrict__ Wv, const float* __restrict__ Wo,
    short* __restrict__ Uth, short* __restrict__ Utl, float* __restrict__ consts,
    short* __restrict__ xh,
    short* __restrict__ Wvh, short* __restrict__ Woh) {
  __shared__ float wv[390];
  __shared__ float tile[64][65];
  int bx = blockIdx.x, t = threadIdx.x;
  if (bx < 96) {
    if (t < 128) {
      float wp = 0.f;
      for (int j = 0; j < 64; ++j) wp += Wphi_in[t*64+j] * Wphi_out[j];
      float wt = 0.f;
      for (int j = 0; j < 32; ++j) wt += Wtau_in[t*32+j] * Wtau_out[j];
      wv[t]       = wp;
      wv[128 + t] = Wta[t] + Wtb[t];     // T_SCALAR == 1
      wv[256 + t] = wt;
    } else if (t == 128) {
      float bp = bphi_out[0];
      for (int j = 0; j < 64; ++j) bp += bphi_in[j]*Wphi_out[j];
      float bt = btau_out[0];
      for (int j = 0; j < 32; ++j) bt += btau_in[j]*Wtau_out[j];
      wv[384] = bp;
      wv[385] = bta[0] + btb[0];
      wv[386] = bt;
    }
    __syncthreads();
    int idx = bx*256 + t;              // 0..24575
    int c = idx & 511;
    int s = idx >> 9;
    int h = s / 6, tt = s % 6;
    int qk = tt / 3;
    int which = tt % 3;
    float scale = (which == 2) ? LOG2E : -LOG2E;
    const float* W = qk ? Wk : Wq;
    const float* wvec = wv + which*128 + qk*64;
    const float* row = W + c*512 + h*64;
    float acc = 0.f;
    #pragma unroll 8
    for (int d = 0; d < 64; ++d) acc += row[d] * wvec[d];
    float v = acc * scale;
    short hi = bf16r(v);
    Uth[s*512 + c] = hi;
    Utl[s*512 + c] = bf16r(v - bf16f(hi));
    if (c == 0) {
      const float* bb = qk ? bk : bq;
      float cs = 0.f;
      for (int d = 0; d < 64; ++d) cs += bb[h*64+d] * wvec[d];
      if (qk == 0) cs += wv[384 + which];
      consts[s] = cs * scale;
    }
    return;
  }
  if (bx < 1120) {
    size_t i = (size_t)((bx-96)*256 + t) * 8;
    float4 a = *(const float4*)(x + i);
    float4 b = *(const float4*)(x + i + 4);
    float vals[8] = {a.x,a.y,a.z,a.w,b.x,b.y,b.z,b.w};
    v8s hi;
    #pragma unroll
    for (int j = 0; j < 8; ++j) hi[j] = bf16r(vals[j]);
    *(v8s*)(xh + i) = hi;
    return;
  }
  int idx = bx - 1120;              // 0..127
  int z = idx >> 6, rem = idx & 63;
  int k0 = (rem >> 3)*64, n0 = (rem & 7)*64;
  const float* src = z ? Wo : Wv;
  short* dh = z ? Woh : Wvh;
  int kr = t >> 2, cq = t & 3;
  #pragma unroll
  for (int i = 0; i < 4; ++i) {
    float4 v = *(const float4*)(src + (size_t)(k0+kr)*512 + n0 + cq*16 + i*4);
    tile[kr][cq*16+i*4+0] = v.x; tile[kr][cq*16+i*4+1] = v.y;
    tile[kr][cq*16+i*4+2] = v.z; tile[kr][cq*16+i*4+3] = v.w;
  }
  __syncthreads();
  int nr = t >> 2, ko = t & 3;
  v8s h0,h1;
  #pragma unroll
  for (int i = 0; i < 8; ++i) {
    h0[i] = bf16r(tile[ko*16+i][nr]);
    h1[i] = bf16r(tile[ko*16+8+i][nr]);
  }
  size_t base = (size_t)(n0+nr)*512 + k0 + ko*16;
  *(v8s*)(dh + base) = h0; *(v8s*)(dh + base + 8) = h1;
}

// ---------------------------------------------------------------------------
// LDS-staged single-product MFMA GEMM: C = A*B + bias (A, B single bf16
// planes). Register-prefetch of next K-tile; 2 staged arrays; 4 MFMA/K-step.
// MODE 0: fp32 C + bias.  MODE 1: bf16 VT[b*8+h][d][t] (BN=64 = one head).
template<int MODE>
__device__ __forceinline__ void gemm_body(char* smem, int mb, int nb,
    const short* __restrict__ A, const short* __restrict__ B,
    const float* __restrict__ bias, float* __restrict__ C, short* __restrict__ VT) {
  short (*As)[40] = (short(*)[40])(smem);
  short (*Bs)[40] = (short(*)[40])(smem + 5120);
  int tid = threadIdx.x, l = tid & 63, ra = l & 15, kg = l >> 4;
  int w = tid >> 6, wr = w >> 1, wc = w & 1;
  v4f acc[2][2] = {};
  int srow = tid >> 2, soct = tid & 3;
  const short* gA = A + (size_t)(mb*64+srow)*512 + soct*8;
  const short* gB = B + (size_t)(nb*64+srow)*512 + soct*8;
  v8s sa = *(const v8s*)(gA);
  v8s sc = *(const v8s*)(gB);
  for (int k0 = 0; k0 < 512; k0 += 32) {
    __syncthreads();
    *(v8s*)&As[srow][soct*8] = sa;
    *(v8s*)&Bs[srow][soct*8] = sc;
    if (k0 < 480) {                       // prefetch next K-tile into regs
      sa = *(const v8s*)(gA + k0 + 32);
      sc = *(const v8s*)(gB + k0 + 32);
    }
    __syncthreads();
    v8s a[2], b[2];
    #pragma unroll
    for (int mi = 0; mi < 2; ++mi)
      a[mi] = *(const v8s*)&As[wr*32 + mi*16 + ra][kg*8];
    #pragma unroll
    for (int ni = 0; ni < 2; ++ni)
      b[ni] = *(const v8s*)&Bs[wc*32 + ni*16 + ra][kg*8];
    #pragma unroll
    for (int mi = 0; mi < 2; ++mi)
      #pragma unroll
      for (int ni = 0; ni < 2; ++ni)
        acc[mi][ni] = __builtin_amdgcn_mfma_f32_16x16x32_bf16(a[mi], b[ni], acc[mi][ni], 0, 0, 0);
  }
  if constexpr (MODE == 0) {
    #pragma unroll
    for (int ni = 0; ni < 2; ++ni) {
      int n = nb*64 + wc*32 + ni*16 + ra;
      float bv_ = bias[n];
      #pragma unroll
      for (int mi = 0; mi < 2; ++mi) {
        int row = mb*64 + wr*32 + mi*16 + kg*4;
        #pragma unroll
        for (int r = 0; r < 4; ++r)
          C[(size_t)(row+r)*512 + n] = acc[mi][ni][r] + bv_;
      }
    }
  } else {
    __syncthreads();                      // staging reads done; alias ldsT
    float (*ldsT)[65] = (float(*)[65])(smem);
    #pragma unroll
    for (int ni = 0; ni < 2; ++ni) {
      int lc = wc*32 + ni*16 + ra;
      float bv_ = bias[nb*64 + lc];
      #pragma unroll
      for (int mi = 0; mi < 2; ++mi) {
        int lr = wr*32 + mi*16 + kg*4;
        #pragma unroll
        for (int r = 0; r < 4; ++r)
          ldsT[lc][lr+r] = acc[mi][ni][r] + bv_;
      }
    }
    __syncthreads();
    int d = tid >> 2, tq = tid & 3;
    v8s h0, h1;
    #pragma unroll
    for (int i = 0; i < 8; ++i) {
      h0[i] = bf16r(ldsT[d][tq*16+i]);
      h1[i] = bf16r(ldsT[d][tq*16+8+i]);
    }
    size_t base = ((size_t)(((mb>>4)*8 + nb)*64 + d))*1024 + (mb&15)*64 + tq*16;
    *(v8s*)(VT + base)     = h0;
    *(v8s*)(VT + base + 8) = h1;
  }
}

// ---------------------------------------------------------------------------
// E[s][tok] = exp2(xh . (Uth+Utl)[s] + consts[s]); 16 rows/block.
// Q-side S errors are row-constant (cancel in softmax); K-side average out.
__device__ __forceinline__ void S_body(char* smem, int mb,
    const short* __restrict__ xh,
    const short* __restrict__ Uth, const short* __restrict__ Utl,
    const float* __restrict__ consts, float* __restrict__ E) {
  float* red = (float*)smem;            // [3][64][12]
  int tid = threadIdx.x, w = tid >> 6, l = tid & 63, ra = l & 15, kg = l >> 4;
  v4f acc[3] = {{0,0,0,0},{0,0,0,0},{0,0,0,0}};
  const short* xa = xh + (size_t)(mb*16+ra)*512;
  #pragma unroll
  for (int ks = 0; ks < 4; ++ks) {
    int kk = w*128 + ks*32 + kg*8;
    v8s ah = *(const v8s*)(xa + kk);
    #pragma unroll
    for (int nf = 0; nf < 3; ++nf) {
      v8s bh = *(const v8s*)(Uth + (size_t)(nf*16+ra)*512 + kk);
      v8s bl = *(const v8s*)(Utl + (size_t)(nf*16+ra)*512 + kk);
      acc[nf] = __builtin_amdgcn_mfma_f32_16x16x32_bf16(ah, bh, acc[nf], 0, 0, 0);
      acc[nf] = __builtin_amdgcn_mfma_f32_16x16x32_bf16(ah, bl, acc[nf], 0, 0, 0);
    }
  }
  if (w > 0) {
    #pragma unroll
    for (int nf = 0; nf < 3; ++nf) *(v4f*)(red + ((w-1)*64 + l)*12 + nf*4) = acc[nf];
  }
  __syncthreads();
  if (w == 0) {
    #pragma unroll
    for (int p = 0; p < 3; ++p)
      #pragma unroll
      for (int nf = 0; nf < 3; ++nf) acc[nf] += *(const v4f*)(red + (p*64 + l)*12 + nf*4);
    int t0 = mb*16 + kg*4;
    #pragma unroll
    for (int nf = 0; nf < 3; ++nf) {
      int s = nf*16 + ra;
      float cns = consts[s];
      v4f o;
      #pragma unroll
      for (int c = 0; c < 4; ++c) o[c] = __builtin_amdgcn_exp2f(acc[nf][c] + cns);
      *(v4f*)(E + (size_t)s*NTOK + t0) = o;
    }
  }
}

// Fused mid stage: [0,256) = S/E planes; [256,768) = V-GEMM (MODE 1).
__global__ __launch_bounds__(256) void k_mid(
    const short* __restrict__ xh,
    const short* __restrict__ Uth, const short* __restrict__ Utl,
    const float* __restrict__ consts, float* __restrict__ E,
    const short* __restrict__ Wvh,
    const float* __restrict__ bv, short* __restrict__ VT) {
  __shared__ __align__(16) char smem[16640];
  int bx = blockIdx.x;
  if (bx < 256) {
    S_body(smem, bx, xh, Uth, Utl, consts, E);
  } else {
    int i = bx - 256;
    gemm_body<1>(smem, i >> 3, i & 7, xh, Wvh, bv, nullptr, VT);
  }
}

// ---------------------------------------------------------------------------
__global__ __launch_bounds__(256) void k_out(
    const short* __restrict__ A, const short* __restrict__ B,
    const float* __restrict__ bias, float* __restrict__ C) {
  __shared__ __align__(16) char smem[16640];
  gemm_body<0>(smem, blockIdx.x, blockIdx.y, A, B, bias, C, nullptr);
}

// ---------------------------------------------------------------------------
// MFMA flash attention (best-measured structure, unchanged): 32 q-rows/block,
// 4 B-frags shared across 2 A-frags, split-K x4, LDS combine, AOh-only out.
__global__ __launch_bounds__(256) void k_attn(const float* __restrict__ E,
                                              const short* __restrict__ VT,
                                              short* __restrict__ AOh) {
  __shared__ float red[3][64][40];
  int tid = threadIdx.x, w = tid >> 6, l = tid & 63, ra = l & 15, kg = l >> 4;
  int bh = blockIdx.y, b = bh >> 3, h = bh & 7;
  int q0 = blockIdx.x * 32;
  const float* Eb = E + (size_t)h*6*NTOK + b*T_;
  float eqp[2], eqc[2], eqt[2];
  #pragma unroll
  for (int ai = 0; ai < 2; ++ai) {
    eqp[ai] = Eb[q0 + ai*16 + ra];
    eqc[ai] = Eb[NTOK + q0 + ai*16 + ra];
    eqt[ai] = Eb[2*NTOK + q0 + ai*16 + ra];
  }
  const float* Ekp = Eb + 3*NTOK;
  const float* Ekc = Eb + 4*NTOK;
  const float* Ekt = Eb + 5*NTOK;
  const short* Vb = VT + (size_t)bh*64*1024 + (size_t)ra*1024;

  v4f acc[2][4] = {};
  v4f dacc[2] = {};
  v8s ones;
  #pragma unroll
  for (int j = 0; j < 8; ++j) ones[j] = (short)0x3F80;

  #pragma unroll 2
  for (int ks = 0; ks < 8; ++ks) {
    int kk = w*256 + ks*32 + kg*8;
    v4f p0 = *(const v4f*)&Ekp[kk], p1 = *(const v4f*)&Ekp[kk+4];
    v4f c0 = *(const v4f*)&Ekc[kk], c1 = *(const v4f*)&Ekc[kk+4];
    v4f t0 = *(const v4f*)&Ekt[kk], t1 = *(const v4f*)&Ekt[kk+4];
    v8s bfr[4];
    #pragma unroll
    for (int ni = 0; ni < 4; ++ni) bfr[ni] = *(const v8s*)(Vb + (size_t)ni*16*1024 + kk);
    #pragma unroll
    for (int ai = 0; ai < 2; ++ai) {
      float p8[8];
      #pragma unroll
      for (int j = 0; j < 8; ++j) {
        float Ep = (j < 4) ? p0[j] : p1[j-4];
        float Ec = (j < 4) ? c0[j] : c1[j-4];
        float Et = (j < 4) ? t0[j] : t1[j-4];
        float ephi = eqp[ai] * Ep;                               // e^{-a_phi}
        float ec   = eqc[ai] * Ec;                               // e^{-a_c}
        float g    = eqt[ai] * Et;                               // e^{a_tau}
        float ti   = __builtin_amdgcn_rcpf(1.f + ec);            // sigmoid(a_c)
        float t2   = __builtin_amdgcn_logf(1.f + g);             // softplus/ln2
        float z    = 1.f - __builtin_amdgcn_exp2f(-t2 * ti);
        float den  = (1.f + ephi) * fmaf(t2, LN2SQ, 6.93e-7f);
        p8[j] = __builtin_amdgcn_exp2f(z * __builtin_amdgcn_rcpf(den));
      }
      union { unsigned u[4]; v8s s; } af;
      af.u[0] = cvt_pk_bf16(p8[0], p8[1]);
      af.u[1] = cvt_pk_bf16(p8[2], p8[3]);
      af.u[2] = cvt_pk_bf16(p8[4], p8[5]);
      af.u[3] = cvt_pk_bf16(p8[6], p8[7]);
      v8s afrag = af.s;
      #pragma unroll
      for (int ni = 0; ni < 4; ++ni)
        acc[ai][ni] = __builtin_amdgcn_mfma_f32_16x16x32_bf16(afrag, bfr[ni], acc[ai][ni], 0, 0, 0);
      dacc[ai] = __builtin_amdgcn_mfma_f32_16x16x32_bf16(afrag, ones, dacc[ai], 0, 0, 0);
    }
  }

  if (w > 0) {
    float* rp = &red[w-1][l][0];
    #pragma unroll
    for (int ai = 0; ai < 2; ++ai) {
      #pragma unroll
      for (int ni = 0; ni < 4; ++ni) *(v4f*)(rp + ai*16 + ni*4) = acc[ai][ni];
      *(v4f*)(rp + 32 + ai*4) = dacc[ai];
    }
  }
  __syncthreads();
  if (w == 0) {
    #pragma unroll
    for (int p = 0; p < 3; ++p) {
      const float* rp = &red[p][l][0];
      #pragma unroll
      for (int ai = 0; ai < 2; ++ai) {
        #pragma unroll
        for (int ni = 0; ni < 4; ++ni) acc[ai][ni] += *(const v4f*)(rp + ai*16 + ni*4);
        dacc[ai] += *(const v4f*)(rp + 32 + ai*4);
      }
    }
    #pragma unroll
    for (int ai = 0; ai < 2; ++ai) {
      size_t qb = (size_t)(b*T_ + q0 + ai*16 + kg*4);
      #pragma unroll
      for (int r = 0; r < 4; ++r) {
        float inv = __builtin_amdgcn_rcpf(dacc[ai][r]);
        size_t o = (qb + r)*512 + h*64 + ra;
        #pragma unroll
        for (int ni = 0; ni < 4; ++ni)
          AOh[o + ni*16] = bf16r(acc[ai][ni][r] * inv);
      }
    }
  }
}

// ---------------------------------------------------------------------------
extern "C" void kernel_launch(void* const* d_in, const int* in_sizes, int n_in,
                              void* d_out, int out_size, void* d_ws, size_t ws_size,
                              hipStream_t stream) {
  (void)in_sizes; (void)n_in; (void)out_size; (void)ws_size;
  const float* x        = (const float*)d_in[0];
  const float* Wq       = (const float*)d_in[1];
  const float* bq       = (const float*)d_in[2];
  const float* Wk       = (const float*)d_in[3];
  const float* bk       = (const float*)d_in[4];
  const float* Wv       = (const float*)d_in[5];
  const float* bv       = (const float*)d_in[6];
  const float* Wphi_in  = (const float*)d_in[7];
  const float* bphi_in  = (const float*)d_in[8];
  const float* Wphi_out = (const float*)d_in[9];
  const float* bphi_out = (const float*)d_in[10];
  const float* Wta      = (const float*)d_in[11];
  const float* bta      = (const float*)d_in[12];
  const float* Wtb      = (const float*)d_in[13];
  const float* btb      = (const float*)d_in[14];
  const float* Wtau_in  = (const float*)d_in[15];
  const float* btau_in  = (const float*)d_in[16];
  const float* Wtau_out = (const float*)d_in[17];
  const float* btau_out = (const float*)d_in[18];
  const float* Wo       = (const float*)d_in[19];
  const float* bo       = (const float*)d_in[20];
  float* out = (float*)d_out;
  float* ws  = (float*)d_ws;

  float* consts = ws + CONST_OFF;
  short* Uth    = (short*)(ws + UTH_OFF);
  short* Utl    = (short*)(ws + UTL_OFF);
  short* xhi    = (short*)(ws + XHI_OFF);
  short* AOh    = (short*)(ws + XHI_OFF);   // alias: xh dead after k_mid
  short* Wvth   = (short*)(ws + WVTH_OFF);
  short* Woth   = (short*)(ws + WOTH_OFF);
  float* E      = ws + S_OFF;
  short* VT     = (short*)(ws + VT_OFF);

  hipLaunchKernelGGL(k_prep, dim3(1248), dim3(256), 0, stream,
                     Wphi_in, Wphi_out, bphi_in, bphi_out, Wta, bta, Wtb, btb,
                     Wtau_in, Wtau_out, btau_in, btau_out,
                     Wq, bq, Wk, bk, x, Wv, Wo,
                     Uth, Utl, consts, xhi, Wvth, Woth);
  hipLaunchKernelGGL(k_mid, dim3(768), dim3(256), 0, stream,
                     xhi, Uth, Utl, consts, E, Wvth, bv, VT);
  hipLaunchKernelGGL(k_attn, dim3(T_/32, B_*H_), dim3(256), 0, stream, E, VT, AOh);
  hipLaunchKernelGGL(k_out, dim3(NTOK/64, 8), dim3(256), 0, stream,
                     AOh, Woth, bo, out);
}